// Round 4
// baseline (5884.885 us; speedup 1.0000x reference)
//
#include <hip/hip_runtime.h>
#include <hip/hip_bf16.h>

// ---------------------------------------------------------------------------
// GRU with per-timestep BatchNorm on the input projections.
//   T=512, B=64, I=H=512.
// Round 3 -> 4: barriers were dominated by fence cache-maintenance (release =
// L2 writeback, acquire = full buffer_inv, x2 per step x 32 CUs). Now ALL
// cross-WG payload (hbuf/rhbuf) moves via RELAXED agent-scope atomics (LLC-
// resident, bypassing non-coherent L1/L2) and there are NO fences at all:
//   writer: relaxed payload stores -> vmcnt(0) drain (__syncthreads does it)
//           -> relaxed flag store (per-WG epoch, own 128B line)
//   reader: 32-lane parallel relaxed flag poll -> compiler barrier ->
//           relaxed payload loads (control-dependent, LLC-coherent).
// hbuf/rhbuf are u32[64][256] (= bf16[64][512] byte-identical); lane pairs
// pack column pairs via shfl_xor so stores are 4B atomics; fragment reads are
// 2x u64 relaxed loads. Numerics identical to round 3.
// ---------------------------------------------------------------------------

using bf16x8 = __attribute__((ext_vector_type(8))) short;
using f32x4  = __attribute__((ext_vector_type(4))) float;
using fvec4  = __attribute__((ext_vector_type(4))) float;
using s16x4  = __attribute__((ext_vector_type(4))) short;

#define NWG 32

static __device__ __forceinline__ unsigned short f2bf(float f) {
  union { float ff; unsigned int i; } v; v.ff = f;
  unsigned int x = v.i;
  x += 0x7fffu + ((x >> 16) & 1u);   // RNE
  return (unsigned short)(x >> 16);
}
static __device__ __forceinline__ float h2f(unsigned short u) {
  union { unsigned short s; _Float16 h; } v; v.s = u; return (float)v.h;
}
static __device__ __forceinline__ unsigned short f2h(float f) {
  union { unsigned short s; _Float16 h; } v; v.h = (_Float16)f; return v.s;
}
static __device__ __forceinline__ float sigmoidf_(float x) {
  return 1.0f / (1.0f + __expf(-x));
}
static __device__ __forceinline__ float tanhf_(float x) {
  return 2.0f / (1.0f + __expf(-2.0f * x)) - 1.0f;
}

// ---------------- phase 1: ub_m = BN(x @ U_m^T) + W_m_b  (fp16 out) --------
// 64x64 tile = one timestep x batch(64) x 64 cols. BK=64, 4 waves,
// mfma_f32_16x16x32_bf16. BN stats from fp32 accs: shfl over kseg (16 rows)
// then LDS over the 4 waves (64 rows). Output layout [t][col][batch].
__global__ __launch_bounds__(256) void proj_gemm(
    const float* __restrict__ x,
    const float* __restrict__ Uz, const float* __restrict__ Ur,
    const float* __restrict__ Uh,
    const float* __restrict__ Wzb, const float* __restrict__ Wrb,
    const float* __restrict__ Whb,
    const float* __restrict__ gamma, const float* __restrict__ beta,
    unsigned short* __restrict__ ubz, unsigned short* __restrict__ ubr,
    unsigned short* __restrict__ ubh)
{
  const int mt = blockIdx.x, nt = blockIdx.y, mat = blockIdx.z;
  const float* U  = (mat == 0) ? Uz  : (mat == 1 ? Ur  : Uh);
  const float* Wb = (mat == 0) ? Wzb : (mat == 1 ? Wrb : Whb);
  unsigned short* uo = (mat == 0) ? ubz : (mat == 1 ? ubr : ubh);

  __shared__ short lA[4096];   // [64][64] bf16, 128B rows, XOR-swizzled
  __shared__ short lB[4096];

  const int tid = threadIdx.x;
  const int wave = tid >> 6, lane = tid & 63;
  const int fl = lane & 15, kseg = lane >> 4;

  f32x4 acc[4];
  #pragma unroll
  for (int n = 0; n < 4; ++n) acc[n] = f32x4{0.f, 0.f, 0.f, 0.f};

  const float* xb = x + (size_t)mt * 64 * 512;
  const float* Ub = U + (size_t)nt * 64 * 512;

  for (int kt = 0; kt < 8; ++kt) {
    __syncthreads();
    #pragma unroll
    for (int c = 0; c < 2; ++c) {
      const int chunk = tid + 256 * c;       // 0..511
      const int row = chunk >> 3, kc = chunk & 7;
      const int lb = row * 128 + ((kc * 16) ^ ((row & 7) << 4));
      {
        const float* g = xb + (size_t)row * 512 + kt * 64 + kc * 8;
        fvec4 a0 = *(const fvec4*)g, a1 = *(const fvec4*)(g + 4);
        bf16x8 p;
        p[0] = (short)f2bf(a0[0]); p[1] = (short)f2bf(a0[1]);
        p[2] = (short)f2bf(a0[2]); p[3] = (short)f2bf(a0[3]);
        p[4] = (short)f2bf(a1[0]); p[5] = (short)f2bf(a1[1]);
        p[6] = (short)f2bf(a1[2]); p[7] = (short)f2bf(a1[3]);
        *(bf16x8*)((char*)lA + lb) = p;
      }
      {
        const float* g = Ub + (size_t)row * 512 + kt * 64 + kc * 8;
        fvec4 a0 = *(const fvec4*)g, a1 = *(const fvec4*)(g + 4);
        bf16x8 p;
        p[0] = (short)f2bf(a0[0]); p[1] = (short)f2bf(a0[1]);
        p[2] = (short)f2bf(a0[2]); p[3] = (short)f2bf(a0[3]);
        p[4] = (short)f2bf(a1[0]); p[5] = (short)f2bf(a1[1]);
        p[6] = (short)f2bf(a1[2]); p[7] = (short)f2bf(a1[3]);
        *(bf16x8*)((char*)lB + lb) = p;
      }
    }
    __syncthreads();
    #pragma unroll
    for (int kk = 0; kk < 2; ++kk) {
      const int ar = wave * 16 + fl;
      bf16x8 af = *(const bf16x8*)((char*)lA + ar * 128 +
                    ((kk * 64 + kseg * 16) ^ ((ar & 7) << 4)));
      #pragma unroll
      for (int n = 0; n < 4; ++n) {
        const int br = n * 16 + fl;
        bf16x8 bfr = *(const bf16x8*)((char*)lB + br * 128 +
                      ((kk * 64 + kseg * 16) ^ ((br & 7) << 4)));
        acc[n] = __builtin_amdgcn_mfma_f32_16x16x32_bf16(af, bfr, acc[n], 0, 0, 0);
      }
    }
  }

  // ---- BN epilogue: exact batch stats (all 64 rows), from fp32 accs ----
  float sn[4], qn[4];
  #pragma unroll
  for (int n = 0; n < 4; ++n) {
    sn[n] = acc[n][0] + acc[n][1] + acc[n][2] + acc[n][3];
    qn[n] = acc[n][0]*acc[n][0] + acc[n][1]*acc[n][1]
          + acc[n][2]*acc[n][2] + acc[n][3]*acc[n][3];
    sn[n] += __shfl_xor(sn[n], 16); qn[n] += __shfl_xor(qn[n], 16);
    sn[n] += __shfl_xor(sn[n], 32); qn[n] += __shfl_xor(qn[n], 32);
  }
  __syncthreads();                       // all MFMA LDS reads done; reuse lA/lB
  float* sArr = (float*)lA;              // [wave*64 + n*16 + fl]
  float* qArr = (float*)lB;
  if (kseg == 0) {
    #pragma unroll
    for (int n = 0; n < 4; ++n) {
      sArr[wave * 64 + n * 16 + fl] = sn[n];
      qArr[wave * 64 + n * 16 + fl] = qn[n];
    }
  }
  __syncthreads();

  const int c0 = nt * 64;
  const int b0 = wave * 16 + kseg * 4;     // batch base for this thread
  #pragma unroll
  for (int n = 0; n < 4; ++n) {
    const int idx = n * 16 + fl;
    const float s = sArr[idx] + sArr[64+idx] + sArr[128+idx] + sArr[192+idx];
    const float q = qArr[idx] + qArr[64+idx] + qArr[128+idx] + qArr[192+idx];
    const float mu = s * 0.015625f;
    const float rs = rsqrtf(q * 0.015625f - mu * mu + 1e-5f);
    const int col = c0 + idx;
    const float gb  = gamma[col] * rs;
    const float ofs = beta[col] + Wb[col] - gb * mu;   // fold W bias here
    s16x4 pk;
    #pragma unroll
    for (int i = 0; i < 4; ++i)
      pk[i] = (short)f2h(gb * acc[n][i] + ofs);
    // transposed layout: [t][col][batch]
    *(s16x4*)(uo + ((size_t)mt * 512 + col) * 64 + b0) = pk;
  }
}

// ---------------- phase 2: persistent GRU scan ----------------
__global__ __launch_bounds__(256) void gru_scan(
    const float* __restrict__ h0,
    const float* __restrict__ Wz, const float* __restrict__ Wr,
    const float* __restrict__ Wh,
    const unsigned short* __restrict__ ubz, const unsigned short* __restrict__ ubr,
    const unsigned short* __restrict__ ubh,
    unsigned int* __restrict__ hbuf, unsigned int* __restrict__ rhbuf,
    unsigned int* __restrict__ flags, float* __restrict__ out)
{
  const int wg = blockIdx.x;           // owns cols [wg*16, wg*16+16)
  const int tid = threadIdx.x;
  const int wave = tid >> 6, lane = tid & 63;
  const int fl = lane & 15, kseg = lane >> 4;
  const int col = wg * 16 + fl;        // this lane's output column
  const int row0 = wave * 16 + kseg * 4;   // first of 4 C-rows (batch)
  const int hrow = wave * 16 + fl;         // A-frag row (batch)

  // W slices, bf16, [mat][16 rows][512 k], 1KB rows, XOR-swizzled
  __shared__ short lW[24576];

  for (int c = tid; c < 3072; c += 256) {        // 8-elem chunks
    const int m = c >> 10, rem = c & 1023;
    const int r = rem >> 6, kc = rem & 63;
    const float* W = (m == 0) ? Wz : (m == 1 ? Wr : Wh);
    const float* g = W + (size_t)(wg * 16 + r) * 512 + kc * 8;
    bf16x8 p;
    #pragma unroll
    for (int j = 0; j < 8; ++j) p[j] = (short)f2bf(g[j]);
    *(bf16x8*)((char*)lW + m * 16384 + r * 1024 + ((kc * 16) ^ ((r & 7) << 4))) = p;
  }

  // ---- coherence-free exchange helpers (all relaxed agent-scope) ----
  // publish 4 bf16 values (rows row0..row0+3 at this lane's col) into a
  // u32[64][256] buffer: lane pairs pack (even col | odd col<<16), stores
  // split between the pair (even lane stores i=0,2; odd i=1,3).
  auto publish4 = [&](unsigned int* buf, const float v0, const float v1,
                      const float v2, const float v3) {
    float vv[4] = {v0, v1, v2, v3};
    #pragma unroll
    for (int i = 0; i < 4; ++i) {
      unsigned int mine = f2bf(vv[i]);
      unsigned int other = (unsigned int)__shfl_xor((int)mine, 1);
      unsigned int word = (fl & 1) ? ((mine << 16) | other)
                                   : (mine | (other << 16));
      if ((fl & 1) == (i & 1))
        __hip_atomic_store(&buf[(row0 + i) * 256 + (col >> 1)], word,
                           __ATOMIC_RELAXED, __HIP_MEMORY_SCOPE_AGENT);
    }
  };
  // read one 16B A-fragment (row hrow, K-chunk kk) as 2 relaxed u64 loads
  auto read_frag = [&](const unsigned int* buf, int kk) -> bf16x8 {
    const unsigned long long* p =
        (const unsigned long long*)buf + hrow * 128 + kk * 8 + kseg * 2;
    union { unsigned long long q[2]; bf16x8 f; } u;
    u.q[0] = __hip_atomic_load(p,     __ATOMIC_RELAXED, __HIP_MEMORY_SCOPE_AGENT);
    u.q[1] = __hip_atomic_load(p + 1, __ATOMIC_RELAXED, __HIP_MEMORY_SCOPE_AGENT);
    return u.f;
  };
  // wait until all 32 per-WG epoch flags reach ev (32-lane parallel poll).
  auto wait_ev = [&](unsigned int ev) {
    if (lane < NWG) {
      while (__hip_atomic_load(&flags[lane << 5], __ATOMIC_RELAXED,
                               __HIP_MEMORY_SCOPE_AGENT) < ev) {}
    }
    asm volatile("" ::: "memory");   // no acquire fence: payload is LLC-resident
  };
  // arrive: drain own stores to LLC, converge, single relaxed flag store.
  auto arrive = [&](unsigned int ev) {
    asm volatile("s_waitcnt vmcnt(0)" ::: "memory");
    __syncthreads();
    if (tid == 0)
      __hip_atomic_store(&flags[wg << 5], ev, __ATOMIC_RELAXED,
                         __HIP_MEMORY_SCOPE_AGENT);
  };

  // own h columns, fp32, never leave registers
  float hown[4];
  #pragma unroll
  for (int i = 0; i < 4; ++i)
    hown[i] = h0[(size_t)(row0 + i) * 512 + col];
  publish4(hbuf, hown[0], hown[1], hown[2], hown[3]);
  arrive(1u);

  // prefetch BN-ed u for t=0 (biases folded; layout [t][col][batch])
  float uzv[4], urv[4], uhv[4];
  {
    const size_t ub = ((size_t)col) * 64 + row0;
    s16x4 az = *(const s16x4*)(ubz + ub);
    s16x4 ar = *(const s16x4*)(ubr + ub);
    s16x4 ah = *(const s16x4*)(ubh + ub);
    #pragma unroll
    for (int i = 0; i < 4; ++i) {
      uzv[i] = h2f((unsigned short)az[i]);
      urv[i] = h2f((unsigned short)ar[i]);
      uhv[i] = h2f((unsigned short)ah[i]);
    }
  }

  for (int t = 0; t < 512; ++t) {
    // ---- wait: h (version t) visible at LLC
    wait_ev(2 * t + 1);

    // ---- phase 1: z, r gates for our 16 columns
    bf16x8 af[16];
    #pragma unroll
    for (int kk = 0; kk < 16; ++kk)
      af[kk] = read_frag(hbuf, kk);

    f32x4 zacc = f32x4{0.f,0.f,0.f,0.f}, racc = f32x4{0.f,0.f,0.f,0.f};
    #pragma unroll
    for (int kk = 0; kk < 16; ++kk) {
      const int wof = (kk * 64 + kseg * 16) ^ ((fl & 7) << 4);
      bf16x8 b0 = *(const bf16x8*)((const char*)lW + fl * 1024 + wof);
      bf16x8 b1 = *(const bf16x8*)((const char*)lW + 16384 + fl * 1024 + wof);
      zacc = __builtin_amdgcn_mfma_f32_16x16x32_bf16(af[kk], b0, zacc, 0, 0, 0);
      racc = __builtin_amdgcn_mfma_f32_16x16x32_bf16(af[kk], b1, racc, 0, 0, 0);
    }

    float z4[4], r4[4];
    #pragma unroll
    for (int i = 0; i < 4; ++i) {
      z4[i] = sigmoidf_(zacc[i] + uzv[i]);
      r4[i] = sigmoidf_(racc[i] + urv[i]);
    }

    // rh slice (own cols, fp32 h from regs)
    publish4(rhbuf, r4[0] * hown[0], r4[1] * hown[1],
                    r4[2] * hown[2], r4[3] * hown[3]);

    // ---- mid barrier: rh complete
    arrive(2u * t + 2u);
    wait_ev(2 * t + 2);

    // ---- phase 2: candidate state
    #pragma unroll
    for (int kk = 0; kk < 16; ++kk)
      af[kk] = read_frag(rhbuf, kk);

    f32x4 hacc = f32x4{0.f,0.f,0.f,0.f};
    #pragma unroll
    for (int kk = 0; kk < 16; ++kk) {
      const int wof = (kk * 64 + kseg * 16) ^ ((fl & 7) << 4);
      bf16x8 b2 = *(const bf16x8*)((const char*)lW + 32768 + fl * 1024 + wof);
      hacc = __builtin_amdgcn_mfma_f32_16x16x32_bf16(af[kk], b2, hacc, 0, 0, 0);
    }

    float hn[4];
    #pragma unroll
    for (int i = 0; i < 4; ++i) {
      const float nb = tanhf_(hacc[i] + uhv[i]);
      hn[i] = (1.f - z4[i]) * hown[i] + z4[i] * nb;
      hown[i] = hn[i];
    }
    publish4(hbuf, hn[0], hn[1], hn[2], hn[3]);

    // ---- end barrier arrival: h (version t+1) at LLC
    arrive(2u * t + 3u);

    // prefetch next step's u during the (upcoming) barrier wait
    if (t + 1 < 512) {
      const size_t ub = ((size_t)(t + 1) * 512 + col) * 64 + row0;
      s16x4 az = *(const s16x4*)(ubz + ub);
      s16x4 ar = *(const s16x4*)(ubr + ub);
      s16x4 ah = *(const s16x4*)(ubh + ub);
      #pragma unroll
      for (int i = 0; i < 4; ++i) {
        uzv[i] = h2f((unsigned short)az[i]);
        urv[i] = h2f((unsigned short)ar[i]);
        uhv[i] = h2f((unsigned short)ah[i]);
      }
    }
    // outputs (fire-and-forget, after arrival): both copies are hs[t]
    {
      const size_t tb = (size_t)t * 64 * 512;
      #pragma unroll
      for (int i = 0; i < 4; ++i) {
        const size_t o = tb + (size_t)(row0 + i) * 512 + col;
        const float v = hn[i];
        out[o] = v;
        out[16777216 + o] = v;
      }
    }
  }
}

extern "C" void kernel_launch(void* const* d_in, const int* in_sizes, int n_in,
                              void* d_out, int out_size, void* d_ws, size_t ws_size,
                              hipStream_t stream) {
  (void)in_sizes; (void)n_in; (void)out_size; (void)ws_size;
  const float* x   = (const float*)d_in[0];
  const float* h0  = (const float*)d_in[1];
  const float* Wz  = (const float*)d_in[2];
  const float* Wzb = (const float*)d_in[3];
  const float* Uz  = (const float*)d_in[4];
  const float* Wr  = (const float*)d_in[6];
  const float* Wrb = (const float*)d_in[7];
  const float* Ur  = (const float*)d_in[8];
  const float* Wh  = (const float*)d_in[10];
  const float* Whb = (const float*)d_in[11];
  const float* Uh  = (const float*)d_in[12];
  const float* gam = (const float*)d_in[14];
  const float* bet = (const float*)d_in[15];
  float* out = (float*)d_out;

  char* ws = (char*)d_ws;
  // layout: [0,8KB) per-WG epoch flags (128B stride) | hbuf 64KB | rhbuf 64KB
  //         | [256KB) ub_z, ub_r, ub_h (fp16 BN-ed + bias, [t][col][b], 32MB)
  unsigned int*   flags = (unsigned int*)(ws);
  unsigned int*   hbuf  = (unsigned int*)(ws + 8192);
  unsigned int*   rhbuf = (unsigned int*)(ws + 8192 + 65536);
  unsigned short* uzb   = (unsigned short*)(ws + 262144);
  unsigned short* urb   = (unsigned short*)(ws + 262144 + 33554432);
  unsigned short* uhb   = (unsigned short*)(ws + 262144 + 2ll * 33554432);

  hipMemsetAsync(flags, 0, 8192, stream);   // epoch flags -> 0

  dim3 gp(512, 8, 3);
  proj_gemm<<<gp, 256, 0, stream>>>(x, Uz, Ur, Uh, Wzb, Wrb, Whb,
                                    gam, bet, uzb, urb, uhb);
  gru_scan<<<dim3(NWG), 256, 0, stream>>>(h0, Wz, Wr, Wh, uzb, urb, uhb,
                                          hbuf, rhbuf, flags, out);
}